// Round 1
// baseline (351.945 us; speedup 1.0000x reference)
//
#include <hip/hip_runtime.h>

#define S_LEN 2048
#define D_MODEL 1024
#define NH 16
#define BATCH 2
#define M_TOK 4096  // BATCH * S_LEN

typedef _Float16 f16;
typedef __attribute__((ext_vector_type(8))) _Float16 f16x8;
typedef __attribute__((ext_vector_type(4))) float f32x4;

__device__ __forceinline__ void gl_lds16(const f16* g, f16* l) {
  __builtin_amdgcn_global_load_lds(
      (const __attribute__((address_space(1))) void*)g,
      (__attribute__((address_space(3))) void*)l, 16, 0, 0);
}

// ---------------- fp32 -> f16 convert (vectorized) ----------------
__global__ void cvt_kernel(const float* __restrict__ in, f16* __restrict__ out, int n4) {
  int i = blockIdx.x * blockDim.x + threadIdx.x;
  int stride = gridDim.x * blockDim.x;
  for (int idx = i; idx < n4; idx += stride) {
    float4 v = ((const float4*)in)[idx];
    union { f16 h[4]; uint2 u; } o;
    o.h[0] = (f16)v.x; o.h[1] = (f16)v.y; o.h[2] = (f16)v.z; o.h[3] = (f16)v.w;
    ((uint2*)out)[idx] = o.u;
  }
}

// ---------------- RoPE sin/cos tables: [S][32] ----------------
__global__ void rope_table_kernel(float* __restrict__ sin_t, float* __restrict__ cos_t) {
  int idx = blockIdx.x * blockDim.x + threadIdx.x;  // S*32 threads
  int s = idx >> 5, i = idx & 31;
  // inv_freq[i] = 10000^(-2*(2i)/64) = 10000^(-i/16)
  float inv = powf(10000.0f, -(float)i * (1.0f / 16.0f));
  float ang = (float)s * inv;
  sin_t[idx] = sinf(ang);
  cos_t[idx] = cosf(ang);
}

// ---------------- GEMM: C[M,N] = A[M,K] * B[N,K]^T + bias ----------------
// M=4096, N=K=1024. 128x128 tile, BK=32, 4 waves (2x2 of 64x64 each).
// EPI: 0 = RoPE epilogue -> f16 [B,H,S,DK];  1 = V-transpose -> f16 [B,H,DK,S];
//      2 = plain fp32 row-major (final output)
template <int EPI>
__global__ __launch_bounds__(256) void gemm_kernel(
    const f16* __restrict__ A, const f16* __restrict__ Bm,
    const float* __restrict__ bias, void* __restrict__ Cout,
    const float* __restrict__ sin_t, const float* __restrict__ cos_t) {
  constexpr int N = D_MODEL, K = D_MODEL;
  __shared__ f16 As[128 * 32];
  __shared__ f16 Bs[128 * 32];
  const int t = threadIdx.x, w = t >> 6, l = t & 63;
  const int bm = blockIdx.x, bn = blockIdx.y;
  const int wr = w >> 1, wc = w & 1;
  const int lr = l & 15, lk = (l >> 4) * 8;

  f32x4 acc[4][4] = {};

  const f16* gA = A + (size_t)(bm * 128 + (t >> 2)) * K + (t & 3) * 8;
  const f16* gB = Bm + (size_t)(bn * 128 + (t >> 2)) * K + (t & 3) * 8;
  f16* lA0 = As + w * 512;
  f16* lA1 = As + 2048 + w * 512;
  f16* lB0 = Bs + w * 512;
  f16* lB1 = Bs + 2048 + w * 512;

  for (int k0 = 0; k0 < K; k0 += 32) {
    gl_lds16(gA, lA0);
    gl_lds16(gA + (size_t)64 * K, lA1);
    gl_lds16(gB, lB0);
    gl_lds16(gB + (size_t)64 * K, lB1);
    gA += 32; gB += 32;
    __syncthreads();
    f16x8 af[4], bf[4];
#pragma unroll
    for (int m = 0; m < 4; m++) af[m] = *(const f16x8*)&As[(wr * 64 + m * 16 + lr) * 32 + lk];
#pragma unroll
    for (int n = 0; n < 4; n++) bf[n] = *(const f16x8*)&Bs[(wc * 64 + n * 16 + lr) * 32 + lk];
#pragma unroll
    for (int m = 0; m < 4; m++)
#pragma unroll
      for (int n = 0; n < 4; n++)
        acc[m][n] = __builtin_amdgcn_mfma_f32_16x16x32_f16(af[m], bf[n], acc[m][n], 0, 0, 0);
    __syncthreads();
  }

  // epilogue: C layout per 16x16 tile: col = lane&15, row = (lane>>4)*4 + j
#pragma unroll
  for (int m = 0; m < 4; m++) {
    int rbase = bm * 128 + wr * 64 + m * 16 + ((l >> 4) << 2);
#pragma unroll
    for (int n = 0; n < 4; n++) {
      int c = bn * 128 + wc * 64 + n * 16 + lr;
      float bv = bias[c];
#pragma unroll
      for (int j = 0; j < 4; j++) {
        float x = acc[m][n][j] + bv;
        int rr = rbase + j;
        if constexpr (EPI == 2) {
          ((float*)Cout)[(size_t)rr * N + c] = x;
        } else if constexpr (EPI == 1) {
          int b = rr >> 11, s = rr & (S_LEN - 1);
          int h = c >> 6, dk = c & 63;
          ((f16*)Cout)[(((size_t)(b * NH + h)) * 64 + dk) * S_LEN + s] = (f16)x;
        } else {
          float p = __shfl_xor(x, 1);  // pair partner (col ^ 1)
          int b = rr >> 11, s = rr & (S_LEN - 1);
          int h = c >> 6, dk = c & 63;
          float sv = sin_t[s * 32 + (dk >> 1)];
          float cv = cos_t[s * 32 + (dk >> 1)];
          float ov = (dk & 1) ? (p * sv + x * cv) : (x * cv - p * sv);
          ((f16*)Cout)[(((size_t)(b * NH + h)) * S_LEN + s) * 64 + dk] = (f16)ov;
        }
      }
    }
  }
}

// ---------------- causal flash attention ----------------
// Qh,Kh: [B,H,S,64] f16 (RoPE'd, Q pre-scaled here); Vt: [B,H,64,S] f16
// ctx out: [B,S,H*64] f16.  Grid: (S/64, B*H), 256 thr = 4 waves, 16 q-rows/wave.
__global__ __launch_bounds__(256) void attn_kernel(
    const f16* __restrict__ Qh, const f16* __restrict__ Kh,
    const f16* __restrict__ Vt, f16* __restrict__ ctx) {
  __shared__ f16 p_lds[4][16][32];
  const int t = threadIdx.x, w = t >> 6, l = t & 63;
  const int lr = l & 15, lk = (l >> 4) * 8;
  const int bh = blockIdx.y;
  const int b = bh >> 4, h = bh & 15;
  const int q0 = blockIdx.x * 64 + w * 16;

  const f16* Qb = Qh + ((size_t)bh * S_LEN + q0) * 64;
  const f16* Kb = Kh + (size_t)bh * S_LEN * 64;
  const f16* Vb = Vt + (size_t)bh * 64 * S_LEN;

  f16x8 qf0 = *(const f16x8*)(Qb + lr * 64 + lk);
  f16x8 qf1 = *(const f16x8*)(Qb + lr * 64 + 32 + lk);
#pragma unroll
  for (int j = 0; j < 8; j++) { qf0[j] *= (f16)0.125f; qf1[j] *= (f16)0.125f; }

  float mrow[4], lrow[4];
  f32x4 o[4] = {};
#pragma unroll
  for (int j = 0; j < 4; j++) { mrow[j] = -1e30f; lrow[j] = 0.f; }
  const int qrow_base = q0 + ((l >> 4) << 2);

  const int nchunk = (q0 + 47) >> 5;  // ceil((q0+16)/32)
  for (int kc = 0; kc < nchunk; ++kc) {
    const int k0 = kc * 32;
    f32x4 c0 = {}, c1 = {};
    f16x8 kf;
    kf = *(const f16x8*)(Kb + (size_t)(k0 + lr) * 64 + lk);
    c0 = __builtin_amdgcn_mfma_f32_16x16x32_f16(qf0, kf, c0, 0, 0, 0);
    kf = *(const f16x8*)(Kb + (size_t)(k0 + lr) * 64 + 32 + lk);
    c0 = __builtin_amdgcn_mfma_f32_16x16x32_f16(qf1, kf, c0, 0, 0, 0);
    kf = *(const f16x8*)(Kb + (size_t)(k0 + 16 + lr) * 64 + lk);
    c1 = __builtin_amdgcn_mfma_f32_16x16x32_f16(qf0, kf, c1, 0, 0, 0);
    kf = *(const f16x8*)(Kb + (size_t)(k0 + 16 + lr) * 64 + 32 + lk);
    c1 = __builtin_amdgcn_mfma_f32_16x16x32_f16(qf1, kf, c1, 0, 0, 0);

    // causal mask: S tile col = lane&15 (kpos), row = (lane>>4)*4+j (q)
#pragma unroll
    for (int j = 0; j < 4; j++) {
      int qr = qrow_base + j;
      if (k0 + lr > qr) c0[j] = -1e30f;
      if (k0 + 16 + lr > qr) c1[j] = -1e30f;
    }

#pragma unroll
    for (int j = 0; j < 4; j++) {
      float mx = fmaxf(c0[j], c1[j]);
      mx = fmaxf(mx, __shfl_xor(mx, 1));
      mx = fmaxf(mx, __shfl_xor(mx, 2));
      mx = fmaxf(mx, __shfl_xor(mx, 4));
      mx = fmaxf(mx, __shfl_xor(mx, 8));
      float mnew = fmaxf(mrow[j], mx);
      float sc = __expf(mrow[j] - mnew);
      float p0 = __expf(c0[j] - mnew);
      float p1 = __expf(c1[j] - mnew);
      float rs = p0 + p1;
      rs += __shfl_xor(rs, 1);
      rs += __shfl_xor(rs, 2);
      rs += __shfl_xor(rs, 4);
      rs += __shfl_xor(rs, 8);
      lrow[j] = lrow[j] * sc + rs;
      mrow[j] = mnew;
#pragma unroll
      for (int n = 0; n < 4; n++) o[n][j] *= sc;
      p_lds[w][((l >> 4) << 2) + j][lr] = (f16)p0;
      p_lds[w][((l >> 4) << 2) + j][16 + lr] = (f16)p1;
    }
    // wave-internal LDS transpose: P -> A-fragment layout (compiler inserts lgkmcnt)
    f16x8 pa = *(const f16x8*)&p_lds[w][lr][lk];
#pragma unroll
    for (int n = 0; n < 4; n++) {
      f16x8 vf = *(const f16x8*)(Vb + (size_t)(n * 16 + lr) * S_LEN + k0 + lk);
      o[n] = __builtin_amdgcn_mfma_f32_16x16x32_f16(pa, vf, o[n], 0, 0, 0);
    }
  }

  // epilogue: divide by row sum, write ctx [B,S,H*64]
#pragma unroll
  for (int n = 0; n < 4; n++) {
#pragma unroll
    for (int j = 0; j < 4; j++) {
      int s = qrow_base + j;
      float val = o[n][j] / lrow[j];
      ctx[((size_t)(b * S_LEN + s)) * D_MODEL + h * 64 + n * 16 + lr] = (f16)val;
    }
  }
}

extern "C" void kernel_launch(void* const* d_in, const int* in_sizes, int n_in,
                              void* d_out, int out_size, void* d_ws, size_t ws_size,
                              hipStream_t stream) {
  const float* q = (const float*)d_in[0];
  const float* k = (const float*)d_in[1];
  const float* v = (const float*)d_in[2];
  // d_in[3] = mask (causal tril, hardcoded), d_in[4] = max_seq_len (unused)
  const float* Wq = (const float*)d_in[5];
  const float* bq = (const float*)d_in[6];
  const float* Wk = (const float*)d_in[7];
  const float* bk = (const float*)d_in[8];
  const float* Wv = (const float*)d_in[9];
  const float* bv = (const float*)d_in[10];
  const float* Wo = (const float*)d_in[11];
  const float* bo = (const float*)d_in[12];

  char* ws = (char*)d_ws;
  const size_t MB = 1ull << 20;
  f16* qb   = (f16*)(ws + 0 * MB);    // [4096,1024] f16, 8MB each
  f16* kb   = (f16*)(ws + 8 * MB);
  f16* vb   = (f16*)(ws + 16 * MB);
  f16* Wqh  = (f16*)(ws + 24 * MB);   // [1024,1024] f16, 2MB each
  f16* Wkh  = (f16*)(ws + 26 * MB);
  f16* Wvh  = (f16*)(ws + 28 * MB);
  f16* Woh  = (f16*)(ws + 30 * MB);
  f16* Qh   = (f16*)(ws + 32 * MB);   // [B,H,S,64] f16
  f16* Kh   = (f16*)(ws + 40 * MB);
  f16* Vt   = (f16*)(ws + 48 * MB);   // [B,H,64,S] f16
  f16* ctxb = (f16*)(ws + 56 * MB);   // [B,S,D] f16
  float* sin_t = (float*)(ws + 64 * MB);           // [S,32] f32
  float* cos_t = (float*)(ws + 64 * MB + 256 * 1024);
  // total ws use: ~64.5 MB

  const int n4_x = (M_TOK * D_MODEL) / 4;
  const int n4_w = (D_MODEL * D_MODEL) / 4;
  cvt_kernel<<<dim3(1024), dim3(256), 0, stream>>>(q, qb, n4_x);
  cvt_kernel<<<dim3(1024), dim3(256), 0, stream>>>(k, kb, n4_x);
  cvt_kernel<<<dim3(1024), dim3(256), 0, stream>>>(v, vb, n4_x);
  cvt_kernel<<<dim3(512), dim3(256), 0, stream>>>(Wq, Wqh, n4_w);
  cvt_kernel<<<dim3(512), dim3(256), 0, stream>>>(Wk, Wkh, n4_w);
  cvt_kernel<<<dim3(512), dim3(256), 0, stream>>>(Wv, Wvh, n4_w);
  cvt_kernel<<<dim3(512), dim3(256), 0, stream>>>(Wo, Woh, n4_w);
  rope_table_kernel<<<dim3((S_LEN * 32) / 256), dim3(256), 0, stream>>>(sin_t, cos_t);

  dim3 ggrid(M_TOK / 128, D_MODEL / 128);
  gemm_kernel<0><<<ggrid, 256, 0, stream>>>(qb, Wqh, bq, Qh, sin_t, cos_t);
  gemm_kernel<0><<<ggrid, 256, 0, stream>>>(kb, Wkh, bk, Kh, sin_t, cos_t);
  gemm_kernel<1><<<ggrid, 256, 0, stream>>>(vb, Wvh, bv, Vt, nullptr, nullptr);

  attn_kernel<<<dim3(S_LEN / 64, BATCH * NH), 256, 0, stream>>>(Qh, Kh, Vt, ctxb);

  gemm_kernel<2><<<ggrid, 256, 0, stream>>>(ctxb, Woh, bo, d_out, nullptr, nullptr);
}

// Round 2
// 247.061 us; speedup vs baseline: 1.4245x; 1.4245x over previous
//
#include <hip/hip_runtime.h>

#define S_LEN 2048
#define D_MODEL 1024
#define NH 16
#define BATCH 2
#define M_TOK 4096  // BATCH * S_LEN

typedef _Float16 f16;
typedef __attribute__((ext_vector_type(8))) _Float16 f16x8;
typedef __attribute__((ext_vector_type(4))) _Float16 f16x4;
typedef __attribute__((ext_vector_type(4))) float f32x4;
typedef __attribute__((ext_vector_type(16))) float f32x16;
typedef __attribute__((ext_vector_type(2))) unsigned int uint2v;

__device__ __forceinline__ void gl_lds16(const f16* g, f16* l) {
  __builtin_amdgcn_global_load_lds(
      (const __attribute__((address_space(1))) void*)g,
      (__attribute__((address_space(3))) void*)l, 16, 0, 0);
}

// ---------------- fp32 -> f16 convert (vectorized) ----------------
__global__ void cvt_kernel(const float* __restrict__ in, f16* __restrict__ out, int n4) {
  int i = blockIdx.x * blockDim.x + threadIdx.x;
  int stride = gridDim.x * blockDim.x;
  for (int idx = i; idx < n4; idx += stride) {
    float4 v = ((const float4*)in)[idx];
    union { f16 h[4]; uint2 u; } o;
    o.h[0] = (f16)v.x; o.h[1] = (f16)v.y; o.h[2] = (f16)v.z; o.h[3] = (f16)v.w;
    ((uint2*)out)[idx] = o.u;
  }
}

// ---------------- RoPE sin/cos tables: [S][32] ----------------
__global__ void rope_table_kernel(float* __restrict__ sin_t, float* __restrict__ cos_t) {
  int idx = blockIdx.x * blockDim.x + threadIdx.x;  // S*32 threads
  int s = idx >> 5, i = idx & 31;
  float inv = powf(10000.0f, -(float)i * (1.0f / 16.0f));
  float ang = (float)s * inv;
  sin_t[idx] = sinf(ang);
  cos_t[idx] = cosf(ang);
}

// ---------------- GEMM: C[M,N] = A[M,K] * B[N,K]^T + bias ----------------
// M=4096, N=K=1024. 128x128 tile, BK=32, 4 waves (2x2 of 64x64 each).
// EPI: 0 = RoPE epilogue -> f16 [B,H,S,DK];  1 = V-transpose -> f16 [B,H,DK,S];
//      2 = plain fp32 row-major (final output)
template <int EPI>
__global__ __launch_bounds__(256) void gemm_kernel(
    const f16* __restrict__ A, const f16* __restrict__ Bm,
    const float* __restrict__ bias, void* __restrict__ Cout,
    const float* __restrict__ sin_t, const float* __restrict__ cos_t) {
  constexpr int N = D_MODEL, K = D_MODEL;
  __shared__ f16 As[128 * 32];
  __shared__ f16 Bs[128 * 32];
  const int t = threadIdx.x, w = t >> 6, l = t & 63;
  const int bm = blockIdx.x, bn = blockIdx.y;
  const int wr = w >> 1, wc = w & 1;
  const int lr = l & 15, lk = (l >> 4) * 8;

  f32x4 acc[4][4] = {};

  const f16* gA = A + (size_t)(bm * 128 + (t >> 2)) * K + (t & 3) * 8;
  const f16* gB = Bm + (size_t)(bn * 128 + (t >> 2)) * K + (t & 3) * 8;
  f16* lA0 = As + w * 512;
  f16* lA1 = As + 2048 + w * 512;
  f16* lB0 = Bs + w * 512;
  f16* lB1 = Bs + 2048 + w * 512;

  for (int k0 = 0; k0 < K; k0 += 32) {
    gl_lds16(gA, lA0);
    gl_lds16(gA + (size_t)64 * K, lA1);
    gl_lds16(gB, lB0);
    gl_lds16(gB + (size_t)64 * K, lB1);
    gA += 32; gB += 32;
    __syncthreads();
    f16x8 af[4], bf[4];
#pragma unroll
    for (int m = 0; m < 4; m++) af[m] = *(const f16x8*)&As[(wr * 64 + m * 16 + lr) * 32 + lk];
#pragma unroll
    for (int n = 0; n < 4; n++) bf[n] = *(const f16x8*)&Bs[(wc * 64 + n * 16 + lr) * 32 + lk];
#pragma unroll
    for (int m = 0; m < 4; m++)
#pragma unroll
      for (int n = 0; n < 4; n++)
        acc[m][n] = __builtin_amdgcn_mfma_f32_16x16x32_f16(af[m], bf[n], acc[m][n], 0, 0, 0);
    __syncthreads();
  }

  // epilogue: C layout per 16x16 tile: col = lane&15, row = (lane>>4)*4 + j
#pragma unroll
  for (int m = 0; m < 4; m++) {
    int rbase = bm * 128 + wr * 64 + m * 16 + ((l >> 4) << 2);
#pragma unroll
    for (int n = 0; n < 4; n++) {
      int c = bn * 128 + wc * 64 + n * 16 + lr;
      float bv = bias[c];
#pragma unroll
      for (int j = 0; j < 4; j++) {
        float x = acc[m][n][j] + bv;
        int rr = rbase + j;
        if constexpr (EPI == 2) {
          ((float*)Cout)[(size_t)rr * N + c] = x;
        } else if constexpr (EPI == 1) {
          int b = rr >> 11, s = rr & (S_LEN - 1);
          int h = c >> 6, dk = c & 63;
          ((f16*)Cout)[(((size_t)(b * NH + h)) * 64 + dk) * S_LEN + s] = (f16)x;
        } else {
          float p = __shfl_xor(x, 1);  // pair partner (col ^ 1)
          int b = rr >> 11, s = rr & (S_LEN - 1);
          int h = c >> 6, dk = c & 63;
          float sv = sin_t[s * 32 + (dk >> 1)];
          float cv = cos_t[s * 32 + (dk >> 1)];
          float ov = (dk & 1) ? (p * sv + x * cv) : (x * cv - p * sv);
          ((f16*)Cout)[(((size_t)(b * NH + h)) * S_LEN + s) * 64 + dk] = (f16)ov;
        }
      }
    }
  }
}

// ---------------- causal flash attention, swapped-QK^T 32x32 ----------------
// Qh,Kh: [B,H,S,64] f16 (RoPE'd); Vt: [B,H,64,S] f16; ctx out: [B,S,H*64] f16.
// Grid: (S/128, B*H), 256 thr = 4 waves, 32 q-rows/wave. No LDS, no barriers.
// S^T = mfma_32x32x16(A=K, B=Q): lane holds scores for q = q0w + (lane&31),
// k = k0 + (r&3) + 8*(r>>2) + 4*(lane>>5). Row softmax: 15 in-lane ops + 1 shfl_xor(32).
// P -> PV B-frag via cvt_pkrtz pairs + permlane32_swap (T12).
__global__ __launch_bounds__(256) void attn_kernel(
    const f16* __restrict__ Qh, const f16* __restrict__ Kh,
    const f16* __restrict__ Vt, f16* __restrict__ ctx) {
  const int t = threadIdx.x, w = t >> 6, l = t & 63;
  const int lq = l & 31, hi = l >> 5;
  const int bh = blockIdx.y, b = bh >> 4, h = bh & 15;
  const int q0w = (15 - blockIdx.x) * 128 + w * 32;  // reversed: big blocks first
  const int q = q0w + lq;

  const f16* Qb = Qh + ((size_t)bh * S_LEN + q0w) * 64;
  const f16* Kb = Kh + (size_t)bh * S_LEN * 64;
  const f16* Vb = Vt + (size_t)bh * 64 * S_LEN;

  // Q as B-frag: lane holds Q[q0w + lq][ks*16 + hi*8 + j], pre-scaled by 1/sqrt(64)
  f16x8 qf[4];
#pragma unroll
  for (int ks = 0; ks < 4; ks++) {
    qf[ks] = *(const f16x8*)(Qb + (size_t)lq * 64 + ks * 16 + hi * 8);
#pragma unroll
    for (int j = 0; j < 8; j++) qf[ks][j] *= (f16)0.125f;
  }

  f32x16 o[2] = {};  // O^T accum: o[dt][r] = O[d = dt*32 + (r&3)+8*(r>>2)+4*hi][q]
  float m = -1e30f, lsum = 0.f;

  const int nt = q0w / 32 + 1;
  for (int kt = 0; kt < nt; ++kt) {
    const int k0 = kt * 32;
    // ---- QK^T (swapped): 4 contraction slices over DK=64
    f32x16 s = {};
#pragma unroll
    for (int ks = 0; ks < 4; ks++) {
      f16x8 kf = *(const f16x8*)(Kb + (size_t)(k0 + lq) * 64 + ks * 16 + hi * 8);
      s = __builtin_amdgcn_mfma_f32_32x32x16_f16(kf, qf[ks], s, 0, 0, 0);
    }
    // V-frags for PV (issue loads early, independent of softmax)
    f16x8 vf00 = *(const f16x8*)(Vb + (size_t)(0 + lq) * S_LEN + k0 + 0 + hi * 8);
    f16x8 vf01 = *(const f16x8*)(Vb + (size_t)(0 + lq) * S_LEN + k0 + 16 + hi * 8);
    f16x8 vf10 = *(const f16x8*)(Vb + (size_t)(32 + lq) * S_LEN + k0 + 0 + hi * 8);
    f16x8 vf11 = *(const f16x8*)(Vb + (size_t)(32 + lq) * S_LEN + k0 + 16 + hi * 8);

    // ---- causal mask (diagonal tile only)
    if (kt == nt - 1) {
#pragma unroll
      for (int r = 0; r < 16; r++) {
        int kk = k0 + (r & 3) + 8 * (r >> 2) + 4 * hi;
        if (kk > q) s[r] = -1e30f;
      }
    }
    // ---- online softmax with defer-max (T13, THR=8)
    float pmax = s[0];
#pragma unroll
    for (int r = 1; r < 16; r++) pmax = fmaxf(pmax, s[r]);
    pmax = fmaxf(pmax, __shfl_xor(pmax, 32));
    if (!__all(pmax <= m + 8.f)) {
      float mn = fmaxf(m, pmax);
      float sc = __expf(m - mn);
#pragma unroll
      for (int r = 0; r < 16; r++) { o[0][r] *= sc; o[1][r] *= sc; }
      lsum *= sc;
      m = mn;
    }
    float p[16];
    float rs = 0.f;
#pragma unroll
    for (int r = 0; r < 16; r++) { p[r] = __expf(s[r] - m); rs += p[r]; }
    rs += __shfl_xor(rs, 32);
    lsum += rs;

    // ---- pack P into PV B-frag: 8 cvt_pkrtz + 4 permlane32_swap
    unsigned pw[8];
#pragma unroll
    for (int i = 0; i < 8; i++)
      pw[i] = __builtin_bit_cast(unsigned, __builtin_amdgcn_cvt_pkrtz(p[2 * i], p[2 * i + 1]));
    uint2v s02 = __builtin_amdgcn_permlane32_swap(pw[0], pw[2], false, false);
    uint2v s13 = __builtin_amdgcn_permlane32_swap(pw[1], pw[3], false, false);
    uint2v s46 = __builtin_amdgcn_permlane32_swap(pw[4], pw[6], false, false);
    uint2v s57 = __builtin_amdgcn_permlane32_swap(pw[5], pw[7], false, false);
    union BU { unsigned u[4]; f16x8 v; };
    BU b0, b1;
    b0.u[0] = s02[0]; b0.u[1] = s13[0]; b0.u[2] = s02[1]; b0.u[3] = s13[1];
    b1.u[0] = s46[0]; b1.u[1] = s57[0]; b1.u[2] = s46[1]; b1.u[3] = s57[1];

    // ---- PV: O^T += V^T-frag x P^T-frag
    o[0] = __builtin_amdgcn_mfma_f32_32x32x16_f16(vf00, b0.v, o[0], 0, 0, 0);
    o[0] = __builtin_amdgcn_mfma_f32_32x32x16_f16(vf01, b1.v, o[0], 0, 0, 0);
    o[1] = __builtin_amdgcn_mfma_f32_32x32x16_f16(vf10, b0.v, o[1], 0, 0, 0);
    o[1] = __builtin_amdgcn_mfma_f32_32x32x16_f16(vf11, b1.v, o[1], 0, 0, 0);
  }

  // ---- epilogue: O[q][d] = o[dt][r]/lsum; lane writes 8x f16x4 (d runs of 4)
  float inv = 1.0f / lsum;
  f16* crow = ctx + ((size_t)(b * S_LEN + q)) * D_MODEL + h * 64;
#pragma unroll
  for (int dt = 0; dt < 2; dt++) {
#pragma unroll
    for (int g = 0; g < 4; g++) {
      f16x4 ov;
#pragma unroll
      for (int c = 0; c < 4; c++) ov[c] = (f16)(o[dt][g * 4 + c] * inv);
      *(f16x4*)(crow + dt * 32 + g * 8 + hi * 4) = ov;
    }
  }
}

extern "C" void kernel_launch(void* const* d_in, const int* in_sizes, int n_in,
                              void* d_out, int out_size, void* d_ws, size_t ws_size,
                              hipStream_t stream) {
  const float* q = (const float*)d_in[0];
  const float* k = (const float*)d_in[1];
  const float* v = (const float*)d_in[2];
  // d_in[3] = mask (causal tril, hardcoded), d_in[4] = max_seq_len (unused)
  const float* Wq = (const float*)d_in[5];
  const float* bq = (const float*)d_in[6];
  const float* Wk = (const float*)d_in[7];
  const float* bk = (const float*)d_in[8];
  const float* Wv = (const float*)d_in[9];
  const float* bv = (const float*)d_in[10];
  const float* Wo = (const float*)d_in[11];
  const float* bo = (const float*)d_in[12];

  char* ws = (char*)d_ws;
  const size_t MB = 1ull << 20;
  f16* qb   = (f16*)(ws + 0 * MB);    // [4096,1024] f16, 8MB each
  f16* kb   = (f16*)(ws + 8 * MB);
  f16* vb   = (f16*)(ws + 16 * MB);
  f16* Wqh  = (f16*)(ws + 24 * MB);   // [1024,1024] f16, 2MB each
  f16* Wkh  = (f16*)(ws + 26 * MB);
  f16* Wvh  = (f16*)(ws + 28 * MB);
  f16* Woh  = (f16*)(ws + 30 * MB);
  f16* Qh   = (f16*)(ws + 32 * MB);   // [B,H,S,64] f16
  f16* Kh   = (f16*)(ws + 40 * MB);
  f16* Vt   = (f16*)(ws + 48 * MB);   // [B,H,64,S] f16
  f16* ctxb = (f16*)(ws + 56 * MB);   // [B,S,D] f16
  float* sin_t = (float*)(ws + 64 * MB);           // [S,32] f32
  float* cos_t = (float*)(ws + 64 * MB + 256 * 1024);

  const int n4_x = (M_TOK * D_MODEL) / 4;
  const int n4_w = (D_MODEL * D_MODEL) / 4;
  cvt_kernel<<<dim3(1024), dim3(256), 0, stream>>>(q, qb, n4_x);
  cvt_kernel<<<dim3(1024), dim3(256), 0, stream>>>(k, kb, n4_x);
  cvt_kernel<<<dim3(1024), dim3(256), 0, stream>>>(v, vb, n4_x);
  cvt_kernel<<<dim3(512), dim3(256), 0, stream>>>(Wq, Wqh, n4_w);
  cvt_kernel<<<dim3(512), dim3(256), 0, stream>>>(Wk, Wkh, n4_w);
  cvt_kernel<<<dim3(512), dim3(256), 0, stream>>>(Wv, Wvh, n4_w);
  cvt_kernel<<<dim3(512), dim3(256), 0, stream>>>(Wo, Woh, n4_w);
  rope_table_kernel<<<dim3((S_LEN * 32) / 256), dim3(256), 0, stream>>>(sin_t, cos_t);

  dim3 ggrid(M_TOK / 128, D_MODEL / 128);
  gemm_kernel<0><<<ggrid, 256, 0, stream>>>(qb, Wqh, bq, Qh, sin_t, cos_t);
  gemm_kernel<0><<<ggrid, 256, 0, stream>>>(kb, Wkh, bk, Kh, sin_t, cos_t);
  gemm_kernel<1><<<ggrid, 256, 0, stream>>>(vb, Wvh, bv, Vt, nullptr, nullptr);

  attn_kernel<<<dim3(S_LEN / 128, BATCH * NH), 256, 0, stream>>>(Qh, Kh, Vt, ctxb);

  gemm_kernel<2><<<ggrid, 256, 0, stream>>>(ctxb, Woh, bo, d_out, nullptr, nullptr);
}

// Round 3
// 228.689 us; speedup vs baseline: 1.5390x; 1.0803x over previous
//
#include <hip/hip_runtime.h>

#define S_LEN 2048
#define D_MODEL 1024
#define NH 16
#define BATCH 2
#define M_TOK 4096  // BATCH * S_LEN

typedef _Float16 f16;
typedef __attribute__((ext_vector_type(8))) _Float16 f16x8;
typedef __attribute__((ext_vector_type(4))) _Float16 f16x4;
typedef __attribute__((ext_vector_type(4))) float f32x4;
typedef __attribute__((ext_vector_type(16))) float f32x16;
typedef __attribute__((ext_vector_type(2))) unsigned int uint2v;

__device__ __forceinline__ void gl_lds16(const f16* g, f16* l) {
  __builtin_amdgcn_global_load_lds(
      (const __attribute__((address_space(1))) void*)g,
      (__attribute__((address_space(3))) void*)l, 16, 0, 0);
}

// ---------------- fused fp32 -> f16 convert for all 7 tensors ----------------
__global__ void cvt_all_kernel(
    const float* __restrict__ q, const float* __restrict__ k, const float* __restrict__ v,
    const float* __restrict__ Wq, const float* __restrict__ Wk,
    const float* __restrict__ Wv, const float* __restrict__ Wo,
    f16* __restrict__ qb, f16* __restrict__ kb, f16* __restrict__ vb,
    f16* __restrict__ Wqh, f16* __restrict__ Wkh, f16* __restrict__ Wvh,
    f16* __restrict__ Woh) {
  const int NX = (M_TOK * D_MODEL) / 4;    // float4 count per activation
  const int NW = (D_MODEL * D_MODEL) / 4;  // per weight
  const int total = 3 * NX + 4 * NW;
  int stride = gridDim.x * blockDim.x;
  for (int i = blockIdx.x * blockDim.x + threadIdx.x; i < total; i += stride) {
    const float* src; f16* dst; int off;
    if (i < 3 * NX) {
      int ts = i / NX; off = i - ts * NX;
      src = ts == 0 ? q : ts == 1 ? k : v;
      dst = ts == 0 ? qb : ts == 1 ? kb : vb;
    } else {
      int j = i - 3 * NX;
      int ts = j / NW; off = j - ts * NW;
      src = ts == 0 ? Wq : ts == 1 ? Wk : ts == 2 ? Wv : Wo;
      dst = ts == 0 ? Wqh : ts == 1 ? Wkh : ts == 2 ? Wvh : Woh;
    }
    float4 vv = ((const float4*)src)[off];
    union { f16 h[4]; uint2 u; } o;
    o.h[0] = (f16)vv.x; o.h[1] = (f16)vv.y; o.h[2] = (f16)vv.z; o.h[3] = (f16)vv.w;
    ((uint2*)dst)[off] = o.u;
  }
}

// ---------------- RoPE sin/cos tables: [S][32] ----------------
__global__ void rope_table_kernel(float* __restrict__ sin_t, float* __restrict__ cos_t) {
  int idx = blockIdx.x * blockDim.x + threadIdx.x;  // S*32 threads
  int s = idx >> 5, i = idx & 31;
  float inv = powf(10000.0f, -(float)i * (1.0f / 16.0f));
  float ang = (float)s * inv;
  sin_t[idx] = sinf(ang);
  cos_t[idx] = cosf(ang);
}

// ---------------- GEMM: C[M,N] = A[M,K] * B[N,K]^T + bias ----------------
// M=4096, N=K=1024. 128x128 tile, BK=32, 4 waves (2x2 of 64x64 each).
// EPI: 0 = RoPE epilogue -> f16 [B,H,S,DK];  1 = V-transpose -> f16 [B,H,DK,S];
//      2 = plain fp32 row-major (final output)
template <int EPI>
__global__ __launch_bounds__(256) void gemm_kernel(
    const f16* __restrict__ A, const f16* __restrict__ Bm,
    const float* __restrict__ bias, void* __restrict__ Cout,
    const float* __restrict__ sin_t, const float* __restrict__ cos_t) {
  constexpr int N = D_MODEL, K = D_MODEL;
  __shared__ f16 As[128 * 32];
  __shared__ f16 Bs[128 * 32];
  const int t = threadIdx.x, w = t >> 6, l = t & 63;
  const int bm = blockIdx.x, bn = blockIdx.y;
  const int wr = w >> 1, wc = w & 1;
  const int lr = l & 15, lk = (l >> 4) * 8;

  f32x4 acc[4][4] = {};

  const f16* gA = A + (size_t)(bm * 128 + (t >> 2)) * K + (t & 3) * 8;
  const f16* gB = Bm + (size_t)(bn * 128 + (t >> 2)) * K + (t & 3) * 8;
  f16* lA0 = As + w * 512;
  f16* lA1 = As + 2048 + w * 512;
  f16* lB0 = Bs + w * 512;
  f16* lB1 = Bs + 2048 + w * 512;

  for (int k0 = 0; k0 < K; k0 += 32) {
    gl_lds16(gA, lA0);
    gl_lds16(gA + (size_t)64 * K, lA1);
    gl_lds16(gB, lB0);
    gl_lds16(gB + (size_t)64 * K, lB1);
    gA += 32; gB += 32;
    __syncthreads();
    f16x8 af[4], bf[4];
#pragma unroll
    for (int m = 0; m < 4; m++) af[m] = *(const f16x8*)&As[(wr * 64 + m * 16 + lr) * 32 + lk];
#pragma unroll
    for (int n = 0; n < 4; n++) bf[n] = *(const f16x8*)&Bs[(wc * 64 + n * 16 + lr) * 32 + lk];
#pragma unroll
    for (int m = 0; m < 4; m++)
#pragma unroll
      for (int n = 0; n < 4; n++)
        acc[m][n] = __builtin_amdgcn_mfma_f32_16x16x32_f16(af[m], bf[n], acc[m][n], 0, 0, 0);
    __syncthreads();
  }

  // epilogue: C layout per 16x16 tile: col = lane&15, row = (lane>>4)*4 + j
#pragma unroll
  for (int m = 0; m < 4; m++) {
    int rbase = bm * 128 + wr * 64 + m * 16 + ((l >> 4) << 2);
#pragma unroll
    for (int n = 0; n < 4; n++) {
      int c = bn * 128 + wc * 64 + n * 16 + lr;
      float bv = bias[c];
#pragma unroll
      for (int j = 0; j < 4; j++) {
        float x = acc[m][n][j] + bv;
        int rr = rbase + j;
        if constexpr (EPI == 2) {
          ((float*)Cout)[(size_t)rr * N + c] = x;
        } else if constexpr (EPI == 1) {
          int b = rr >> 11, s = rr & (S_LEN - 1);
          int h = c >> 6, dk = c & 63;
          ((f16*)Cout)[(((size_t)(b * NH + h)) * 64 + dk) * S_LEN + s] = (f16)x;
        } else {
          float p = __shfl_xor(x, 1);  // pair partner (col ^ 1)
          int b = rr >> 11, s = rr & (S_LEN - 1);
          int h = c >> 6, dk = c & 63;
          float sv = sin_t[s * 32 + (dk >> 1)];
          float cv = cos_t[s * 32 + (dk >> 1)];
          float ov = (dk & 1) ? (p * sv + x * cv) : (x * cv - p * sv);
          ((f16*)Cout)[(((size_t)(b * NH + h)) * S_LEN + s) * 64 + dk] = (f16)ov;
        }
      }
    }
  }
}

// ---------------- causal flash attention, swapped-QK^T 32x32, k-split x2 ----
// Qh,Kh: [B,H,S,64] f16 (RoPE'd); Vt: [B,H,64,S] f16; ctx out: [B,S,H*64] f16.
// Grid: (64, B*H), 128 thr = 2 waves. Block owns q-chunk cx (32 rows); the two
// waves process halves of its k-tile range as flash partials, then LDS-combine.
// cx flips with (y>>2)&1 so same-CU blocks (dispatch stride 256 = Δy 4) get
// complementary causal weights -> per-CU work uniform.
__global__ __launch_bounds__(128) void attn_kernel(
    const f16* __restrict__ Qh, const f16* __restrict__ Kh,
    const f16* __restrict__ Vt, f16* __restrict__ ctx) {
  __shared__ float o_lds[2048];  // wave1 partial O: [(dt*16+r)*2+hi][lq]
  __shared__ float ml_lds[64];   // wave1 m[32], l[32]
  const int t = threadIdx.x, w = t >> 6, l = t & 63;
  const int lq = l & 31, hi = l >> 5;
  const int bh = blockIdx.y, b = bh >> 4, h = bh & 15;
  const int cx = ((blockIdx.y >> 2) & 1) ? (63 - (int)blockIdx.x) : (int)blockIdx.x;
  const int q0w = cx * 32;
  const int q = q0w + lq;
  const int ntot = cx + 1;         // k-tiles in this chunk's causal range
  const int nA = (ntot + 1) >> 1;  // wave0: [0,nA), wave1: [nA,ntot)
  const int t0 = w ? nA : 0;
  const int t1 = w ? ntot : nA;

  const f16* Qb = Qh + ((size_t)bh * S_LEN + q0w) * 64;
  const f16* Kb = Kh + (size_t)bh * S_LEN * 64;
  const f16* Vb = Vt + (size_t)bh * 64 * S_LEN;

  // Q as B-frag: lane holds Q[q0w+lq][ks*16 + hi*8 + j], pre-scaled by 1/8
  f16x8 qf[4];
#pragma unroll
  for (int ks = 0; ks < 4; ks++) {
    qf[ks] = *(const f16x8*)(Qb + (size_t)lq * 64 + ks * 16 + hi * 8);
#pragma unroll
    for (int j = 0; j < 8; j++) qf[ks][j] *= (f16)0.125f;
  }

  f32x16 o[2] = {};  // O^T accum: o[dt][r] = O[d = dt*32 + (r&3)+8*(r>>2)+4*hi][q]
  float m = -1e30f, lsum = 0.f;

  for (int kt = t0; kt < t1; ++kt) {
    const int k0 = kt * 32;
    // ---- QK^T (swapped): 4 contraction slices over DK=64
    f32x16 s = {};
#pragma unroll
    for (int ks = 0; ks < 4; ks++) {
      f16x8 kf = *(const f16x8*)(Kb + (size_t)(k0 + lq) * 64 + ks * 16 + hi * 8);
      s = __builtin_amdgcn_mfma_f32_32x32x16_f16(kf, qf[ks], s, 0, 0, 0);
    }
    // V-frags for PV (issue loads early, independent of softmax)
    f16x8 vf00 = *(const f16x8*)(Vb + (size_t)(0 + lq) * S_LEN + k0 + 0 + hi * 8);
    f16x8 vf01 = *(const f16x8*)(Vb + (size_t)(0 + lq) * S_LEN + k0 + 16 + hi * 8);
    f16x8 vf10 = *(const f16x8*)(Vb + (size_t)(32 + lq) * S_LEN + k0 + 0 + hi * 8);
    f16x8 vf11 = *(const f16x8*)(Vb + (size_t)(32 + lq) * S_LEN + k0 + 16 + hi * 8);

    // ---- causal mask (diagonal tile only)
    if (kt == cx) {
#pragma unroll
      for (int r = 0; r < 16; r++) {
        int kk = k0 + (r & 3) + 8 * (r >> 2) + 4 * hi;
        if (kk > q) s[r] = -1e30f;
      }
    }
    // ---- online softmax with defer-max (T13, THR=8)
    float pmax = s[0];
#pragma unroll
    for (int r = 1; r < 16; r++) pmax = fmaxf(pmax, s[r]);
    pmax = fmaxf(pmax, __shfl_xor(pmax, 32));
    if (!__all(pmax <= m + 8.f)) {
      float mn = fmaxf(m, pmax);
      float sc = __expf(m - mn);
#pragma unroll
      for (int r = 0; r < 16; r++) { o[0][r] *= sc; o[1][r] *= sc; }
      lsum *= sc;
      m = mn;
    }
    float p[16];
    float rs = 0.f;
#pragma unroll
    for (int r = 0; r < 16; r++) { p[r] = __expf(s[r] - m); rs += p[r]; }
    rs += __shfl_xor(rs, 32);
    lsum += rs;

    // ---- pack P into PV B-frag: 8 cvt_pkrtz + 4 permlane32_swap
    unsigned pw[8];
#pragma unroll
    for (int i = 0; i < 8; i++)
      pw[i] = __builtin_bit_cast(unsigned, __builtin_amdgcn_cvt_pkrtz(p[2 * i], p[2 * i + 1]));
    uint2v s02 = __builtin_amdgcn_permlane32_swap(pw[0], pw[2], false, false);
    uint2v s13 = __builtin_amdgcn_permlane32_swap(pw[1], pw[3], false, false);
    uint2v s46 = __builtin_amdgcn_permlane32_swap(pw[4], pw[6], false, false);
    uint2v s57 = __builtin_amdgcn_permlane32_swap(pw[5], pw[7], false, false);
    union BU { unsigned u[4]; f16x8 v; };
    BU b0, b1;
    b0.u[0] = s02[0]; b0.u[1] = s13[0]; b0.u[2] = s02[1]; b0.u[3] = s13[1];
    b1.u[0] = s46[0]; b1.u[1] = s57[0]; b1.u[2] = s46[1]; b1.u[3] = s57[1];

    // ---- PV: O^T += V^T-frag x P^T-frag
    o[0] = __builtin_amdgcn_mfma_f32_32x32x16_f16(vf00, b0.v, o[0], 0, 0, 0);
    o[0] = __builtin_amdgcn_mfma_f32_32x32x16_f16(vf01, b1.v, o[0], 0, 0, 0);
    o[1] = __builtin_amdgcn_mfma_f32_32x32x16_f16(vf10, b0.v, o[1], 0, 0, 0);
    o[1] = __builtin_amdgcn_mfma_f32_32x32x16_f16(vf11, b1.v, o[1], 0, 0, 0);
  }

  // ---- combine the two waves' partials (wave1 publishes, wave0 merges)
  if (w == 1) {
#pragma unroll
    for (int dt = 0; dt < 2; dt++)
#pragma unroll
      for (int r = 0; r < 16; r++)
        o_lds[((dt * 16 + r) * 2 + hi) * 32 + lq] = o[dt][r];
    if (hi == 0) { ml_lds[lq] = m; ml_lds[32 + lq] = lsum; }
  }
  __syncthreads();
  if (w == 0) {
    float mB = ml_lds[lq], lB = ml_lds[32 + lq];
    float mf = fmaxf(m, mB);
    float sA = __expf(m - mf), sB = __expf(mB - mf);
    float lf = lsum * sA + lB * sB;
    float inv = 1.0f / lf;
    f16* crow = ctx + ((size_t)(b * S_LEN + q)) * D_MODEL + h * 64;
#pragma unroll
    for (int dt = 0; dt < 2; dt++) {
#pragma unroll
      for (int g = 0; g < 4; g++) {
        f16x4 ov;
#pragma unroll
        for (int c = 0; c < 4; c++) {
          int r = g * 4 + c;
          float vB = o_lds[((dt * 16 + r) * 2 + hi) * 32 + lq];
          ov[c] = (f16)((o[dt][r] * sA + vB * sB) * inv);
        }
        *(f16x4*)(crow + dt * 32 + g * 8 + hi * 4) = ov;
      }
    }
  }
}

extern "C" void kernel_launch(void* const* d_in, const int* in_sizes, int n_in,
                              void* d_out, int out_size, void* d_ws, size_t ws_size,
                              hipStream_t stream) {
  const float* q = (const float*)d_in[0];
  const float* k = (const float*)d_in[1];
  const float* v = (const float*)d_in[2];
  // d_in[3] = mask (causal tril, hardcoded), d_in[4] = max_seq_len (unused)
  const float* Wq = (const float*)d_in[5];
  const float* bq = (const float*)d_in[6];
  const float* Wk = (const float*)d_in[7];
  const float* bk = (const float*)d_in[8];
  const float* Wv = (const float*)d_in[9];
  const float* bv = (const float*)d_in[10];
  const float* Wo = (const float*)d_in[11];
  const float* bo = (const float*)d_in[12];

  char* ws = (char*)d_ws;
  const size_t MB = 1ull << 20;
  f16* qb   = (f16*)(ws + 0 * MB);    // [4096,1024] f16, 8MB each
  f16* kb   = (f16*)(ws + 8 * MB);
  f16* vb   = (f16*)(ws + 16 * MB);
  f16* Wqh  = (f16*)(ws + 24 * MB);   // [1024,1024] f16, 2MB each
  f16* Wkh  = (f16*)(ws + 26 * MB);
  f16* Wvh  = (f16*)(ws + 28 * MB);
  f16* Woh  = (f16*)(ws + 30 * MB);
  f16* Qh   = (f16*)(ws + 32 * MB);   // [B,H,S,64] f16
  f16* Kh   = (f16*)(ws + 40 * MB);
  f16* Vt   = (f16*)(ws + 48 * MB);   // [B,H,64,S] f16
  f16* ctxb = (f16*)(ws + 56 * MB);   // [B,S,D] f16
  float* sin_t = (float*)(ws + 64 * MB);           // [S,32] f32
  float* cos_t = (float*)(ws + 64 * MB + 256 * 1024);

  cvt_all_kernel<<<dim3(2048), dim3(256), 0, stream>>>(
      q, k, v, Wq, Wk, Wv, Wo, qb, kb, vb, Wqh, Wkh, Wvh, Woh);
  rope_table_kernel<<<dim3((S_LEN * 32) / 256), dim3(256), 0, stream>>>(sin_t, cos_t);

  dim3 ggrid(M_TOK / 128, D_MODEL / 128);
  gemm_kernel<0><<<ggrid, 256, 0, stream>>>(qb, Wqh, bq, Qh, sin_t, cos_t);
  gemm_kernel<0><<<ggrid, 256, 0, stream>>>(kb, Wkh, bk, Kh, sin_t, cos_t);
  gemm_kernel<1><<<ggrid, 256, 0, stream>>>(vb, Wvh, bv, Vt, nullptr, nullptr);

  attn_kernel<<<dim3(64, BATCH * NH), 128, 0, stream>>>(Qh, Kh, Vt, ctxb);

  gemm_kernel<2><<<ggrid, 256, 0, stream>>>(ctxb, Woh, bo, d_out, nullptr, nullptr);
}

// Round 4
// 159.276 us; speedup vs baseline: 2.2097x; 1.4358x over previous
//
#include <hip/hip_runtime.h>

#define S_LEN 2048
#define D_MODEL 1024
#define NH 16
#define BATCH 2
#define M_TOK 4096  // BATCH * S_LEN

typedef _Float16 f16;
typedef __attribute__((ext_vector_type(8))) _Float16 f16x8;
typedef __attribute__((ext_vector_type(4))) _Float16 f16x4;
typedef __attribute__((ext_vector_type(4))) float f32x4;
typedef __attribute__((ext_vector_type(16))) float f32x16;
typedef __attribute__((ext_vector_type(2))) unsigned int uint2v;

__device__ __forceinline__ void gl_lds16(const f16* g, f16* l) {
  __builtin_amdgcn_global_load_lds(
      (const __attribute__((address_space(1))) void*)g,
      (__attribute__((address_space(3))) void*)l, 16, 0, 0);
}

// ---------------- fused fp32 -> f16 convert for all 7 tensors ----------------
__global__ void cvt_all_kernel(
    const float* __restrict__ q, const float* __restrict__ k, const float* __restrict__ v,
    const float* __restrict__ Wq, const float* __restrict__ Wk,
    const float* __restrict__ Wv, const float* __restrict__ Wo,
    f16* __restrict__ qb, f16* __restrict__ kb, f16* __restrict__ vb,
    f16* __restrict__ Wqh, f16* __restrict__ Wkh, f16* __restrict__ Wvh,
    f16* __restrict__ Woh) {
  const int NX = (M_TOK * D_MODEL) / 4;    // float4 count per activation
  const int NW = (D_MODEL * D_MODEL) / 4;  // per weight
  const int total = 3 * NX + 4 * NW;
  int stride = gridDim.x * blockDim.x;
  for (int i = blockIdx.x * blockDim.x + threadIdx.x; i < total; i += stride) {
    const float* src; f16* dst; int off;
    if (i < 3 * NX) {
      int ts = i / NX; off = i - ts * NX;
      src = ts == 0 ? q : ts == 1 ? k : v;
      dst = ts == 0 ? qb : ts == 1 ? kb : vb;
    } else {
      int j = i - 3 * NX;
      int ts = j / NW; off = j - ts * NW;
      src = ts == 0 ? Wq : ts == 1 ? Wk : ts == 2 ? Wv : Wo;
      dst = ts == 0 ? Wqh : ts == 1 ? Wkh : ts == 2 ? Wvh : Woh;
    }
    float4 vv = ((const float4*)src)[off];
    union { f16 h[4]; uint2 u; } o;
    o.h[0] = (f16)vv.x; o.h[1] = (f16)vv.y; o.h[2] = (f16)vv.z; o.h[3] = (f16)vv.w;
    ((uint2*)dst)[off] = o.u;
  }
}

// ---------------- RoPE sin/cos tables: [S][32] ----------------
__global__ void rope_table_kernel(float* __restrict__ sin_t, float* __restrict__ cos_t) {
  int idx = blockIdx.x * blockDim.x + threadIdx.x;  // S*32 threads
  int s = idx >> 5, i = idx & 31;
  float inv = powf(10000.0f, -(float)i * (1.0f / 16.0f));
  float ang = (float)s * inv;
  sin_t[idx] = sinf(ang);
  cos_t[idx] = cosf(ang);
}

// ---------------- fused Q/K/V projection GEMM ----------------
// C[M,N] = A[M,K] * W[N,K]^T + bias. 128x128 tile, BK=32, 4 waves.
// blockIdx.z: 0 = Q (RoPE -> [B,H,S,64]), 1 = K (RoPE), 2 = V (-> [B,H,64,S])
__global__ __launch_bounds__(256) void qkv_gemm_kernel(
    const f16* __restrict__ qb, const f16* __restrict__ kb, const f16* __restrict__ vb,
    const f16* __restrict__ Wqh, const f16* __restrict__ Wkh, const f16* __restrict__ Wvh,
    const float* __restrict__ bq, const float* __restrict__ bk, const float* __restrict__ bv,
    f16* __restrict__ Qh, f16* __restrict__ Kh, f16* __restrict__ Vt,
    const float* __restrict__ sin_t, const float* __restrict__ cos_t) {
  constexpr int K = D_MODEL;
  const int z = blockIdx.z;
  const f16* A = z == 0 ? qb : z == 1 ? kb : vb;
  const f16* Bm = z == 0 ? Wqh : z == 1 ? Wkh : Wvh;
  const float* bias = z == 0 ? bq : z == 1 ? bk : bv;

  __shared__ f16 As[128 * 32];
  __shared__ f16 Bs[128 * 32];
  const int t = threadIdx.x, w = t >> 6, l = t & 63;
  const int bm = blockIdx.x, bn = blockIdx.y;
  const int wr = w >> 1, wc = w & 1;
  const int lr = l & 15, lk = (l >> 4) * 8;

  f32x4 acc[4][4] = {};

  const f16* gA = A + (size_t)(bm * 128 + (t >> 2)) * K + (t & 3) * 8;
  const f16* gB = Bm + (size_t)(bn * 128 + (t >> 2)) * K + (t & 3) * 8;
  f16* lA0 = As + w * 512;
  f16* lA1 = As + 2048 + w * 512;
  f16* lB0 = Bs + w * 512;
  f16* lB1 = Bs + 2048 + w * 512;

  for (int k0 = 0; k0 < K; k0 += 32) {
    gl_lds16(gA, lA0);
    gl_lds16(gA + (size_t)64 * K, lA1);
    gl_lds16(gB, lB0);
    gl_lds16(gB + (size_t)64 * K, lB1);
    gA += 32; gB += 32;
    __syncthreads();
    f16x8 af[4], bf[4];
#pragma unroll
    for (int m = 0; m < 4; m++) af[m] = *(const f16x8*)&As[(wr * 64 + m * 16 + lr) * 32 + lk];
#pragma unroll
    for (int n = 0; n < 4; n++) bf[n] = *(const f16x8*)&Bs[(wc * 64 + n * 16 + lr) * 32 + lk];
#pragma unroll
    for (int m = 0; m < 4; m++)
#pragma unroll
      for (int n = 0; n < 4; n++)
        acc[m][n] = __builtin_amdgcn_mfma_f32_16x16x32_f16(af[m], bf[n], acc[m][n], 0, 0, 0);
    __syncthreads();
  }

  // epilogue: C layout per 16x16 tile: col = lane&15, row = (lane>>4)*4 + j
#pragma unroll
  for (int m = 0; m < 4; m++) {
    int rbase = bm * 128 + wr * 64 + m * 16 + ((l >> 4) << 2);
#pragma unroll
    for (int n = 0; n < 4; n++) {
      int c = bn * 128 + wc * 64 + n * 16 + lr;
      float bv_ = bias[c];
#pragma unroll
      for (int j = 0; j < 4; j++) {
        float x = acc[m][n][j] + bv_;
        int rr = rbase + j;
        int b = rr >> 11, s = rr & (S_LEN - 1);
        int h = c >> 6, dk = c & 63;
        if (z == 2) {
          Vt[(((size_t)(b * NH + h)) * 64 + dk) * S_LEN + s] = (f16)x;
        } else {
          float p = __shfl_xor(x, 1);  // pair partner (col ^ 1)
          float sv = sin_t[s * 32 + (dk >> 1)];
          float cv = cos_t[s * 32 + (dk >> 1)];
          float ov = (dk & 1) ? (p * sv + x * cv) : (x * cv - p * sv);
          f16* dst = z == 0 ? Qh : Kh;
          dst[(((size_t)(b * NH + h)) * S_LEN + s) * 64 + dk] = (f16)ov;
        }
      }
    }
  }
}

// ---------------- output GEMM: fp32 out ----------------
__global__ __launch_bounds__(256) void out_gemm_kernel(
    const f16* __restrict__ A, const f16* __restrict__ Bm,
    const float* __restrict__ bias, float* __restrict__ Cout) {
  constexpr int N = D_MODEL, K = D_MODEL;
  __shared__ f16 As[128 * 32];
  __shared__ f16 Bs[128 * 32];
  const int t = threadIdx.x, w = t >> 6, l = t & 63;
  const int bm = blockIdx.x, bn = blockIdx.y;
  const int wr = w >> 1, wc = w & 1;
  const int lr = l & 15, lk = (l >> 4) * 8;

  f32x4 acc[4][4] = {};

  const f16* gA = A + (size_t)(bm * 128 + (t >> 2)) * K + (t & 3) * 8;
  const f16* gB = Bm + (size_t)(bn * 128 + (t >> 2)) * K + (t & 3) * 8;
  f16* lA0 = As + w * 512;
  f16* lA1 = As + 2048 + w * 512;
  f16* lB0 = Bs + w * 512;
  f16* lB1 = Bs + 2048 + w * 512;

  for (int k0 = 0; k0 < K; k0 += 32) {
    gl_lds16(gA, lA0);
    gl_lds16(gA + (size_t)64 * K, lA1);
    gl_lds16(gB, lB0);
    gl_lds16(gB + (size_t)64 * K, lB1);
    gA += 32; gB += 32;
    __syncthreads();
    f16x8 af[4], bf[4];
#pragma unroll
    for (int m = 0; m < 4; m++) af[m] = *(const f16x8*)&As[(wr * 64 + m * 16 + lr) * 32 + lk];
#pragma unroll
    for (int n = 0; n < 4; n++) bf[n] = *(const f16x8*)&Bs[(wc * 64 + n * 16 + lr) * 32 + lk];
#pragma unroll
    for (int m = 0; m < 4; m++)
#pragma unroll
      for (int n = 0; n < 4; n++)
        acc[m][n] = __builtin_amdgcn_mfma_f32_16x16x32_f16(af[m], bf[n], acc[m][n], 0, 0, 0);
    __syncthreads();
  }

#pragma unroll
  for (int m = 0; m < 4; m++) {
    int rbase = bm * 128 + wr * 64 + m * 16 + ((l >> 4) << 2);
#pragma unroll
    for (int n = 0; n < 4; n++) {
      int c = bn * 128 + wc * 64 + n * 16 + lr;
      float bv = bias[c];
#pragma unroll
      for (int j = 0; j < 4; j++)
        Cout[(size_t)(rbase + j) * N + c] = acc[m][n][j] + bv;
    }
  }
}

// ---------------- causal flash attention, swapped-QK^T 32x32 ----------------
// Qh,Kh: [B,H,S,64] f16 (RoPE'd); Vt: [B,H,64,S] f16; ctx out: [B,S,H*64] f16.
// 1D grid 2048, 128 thr = 2 waves. XCD-pinned: bh = (slot>>6)*8 + (id&7) so each
// XCD's L2 serves 4 bh (2 MB K/V, L2-resident). cx balance: lo / 63-lo pairs.
// Waves split the causal k-range; LDS combine. K-frags ping-pong prefetched.
__global__ __launch_bounds__(128, 4) void attn_kernel(
    const f16* __restrict__ Qh, const f16* __restrict__ Kh,
    const f16* __restrict__ Vt, f16* __restrict__ ctx) {
  __shared__ float o_lds[2048];  // wave1 partial O: [(dt*16+r)*2+hi][lq]
  __shared__ float ml_lds[64];   // wave1 m[32], l[32]
  const int t = threadIdx.x, w = t >> 6, l = t & 63;
  const int lq = l & 31, hi = l >> 5;
  const int id = blockIdx.x;
  const int xcd = id & 7, slot = id >> 3;
  const int lo = slot & 31, flip = (slot >> 5) & 1;
  const int bh = (slot >> 6) * 8 + xcd;
  const int b = bh >> 4, h = bh & 15;
  const int cx = flip ? 63 - lo : lo;
  const int q0w = cx * 32;
  const int q = q0w + lq;
  const int ntot = cx + 1;         // k-tiles in this chunk's causal range
  const int nA = (ntot + 1) >> 1;  // wave0: [0,nA), wave1: [nA,ntot)
  const int t0 = w ? nA : 0;
  const int t1 = w ? ntot : nA;

  const f16* Qb = Qh + ((size_t)bh * S_LEN + q0w) * 64;
  const f16* Kb = Kh + (size_t)bh * S_LEN * 64;
  const f16* Vb = Vt + (size_t)bh * 64 * S_LEN;

  // Q as B-frag: lane holds Q[q0w+lq][ks*16 + hi*8 + j], pre-scaled by 1/8
  f16x8 qf[4];
#pragma unroll
  for (int ks = 0; ks < 4; ks++) {
    qf[ks] = *(const f16x8*)(Qb + (size_t)lq * 64 + ks * 16 + hi * 8);
#pragma unroll
    for (int j = 0; j < 8; j++) qf[ks][j] *= (f16)0.125f;
  }

  f32x16 o[2] = {};  // O^T accum: o[dt][r] = O[d = dt*32 + (r&3)+8*(r>>2)+4*hi][q]
  float m = -1e30f, lsum = 0.f;

  auto loadK = [&](int kt, f16x8* dst) {
#pragma unroll
    for (int ks = 0; ks < 4; ks++)
      dst[ks] = *(const f16x8*)(Kb + (size_t)(kt * 32 + lq) * 64 + ks * 16 + hi * 8);
  };

  auto body = [&](int kt, f16x8* cur, f16x8* nxt) {
    const int k0 = kt * 32;
    // ---- QK^T (swapped): 4 contraction slices over DK=64
    f32x16 s = {};
#pragma unroll
    for (int ks = 0; ks < 4; ks++)
      s = __builtin_amdgcn_mfma_f32_32x32x16_f16(cur[ks], qf[ks], s, 0, 0, 0);
    // prefetch next K tile (clamped; latency hides under softmax+pack)
    loadK(kt + 1 < t1 ? kt + 1 : kt, nxt);
    // V-frags for PV
    f16x8 vf00 = *(const f16x8*)(Vb + (size_t)(0 + lq) * S_LEN + k0 + 0 + hi * 8);
    f16x8 vf01 = *(const f16x8*)(Vb + (size_t)(0 + lq) * S_LEN + k0 + 16 + hi * 8);
    f16x8 vf10 = *(const f16x8*)(Vb + (size_t)(32 + lq) * S_LEN + k0 + 0 + hi * 8);
    f16x8 vf11 = *(const f16x8*)(Vb + (size_t)(32 + lq) * S_LEN + k0 + 16 + hi * 8);

    // ---- causal mask (diagonal tile only)
    if (kt == cx) {
#pragma unroll
      for (int r = 0; r < 16; r++) {
        int kk = k0 + (r & 3) + 8 * (r >> 2) + 4 * hi;
        if (kk > q) s[r] = -1e30f;
      }
    }
    // ---- online softmax with defer-max (T13, THR=8)
    float pmax = s[0];
#pragma unroll
    for (int r = 1; r < 16; r++) pmax = fmaxf(pmax, s[r]);
    pmax = fmaxf(pmax, __shfl_xor(pmax, 32));
    if (!__all(pmax <= m + 8.f)) {
      float mn = fmaxf(m, pmax);
      float sc = __expf(m - mn);
#pragma unroll
      for (int r = 0; r < 16; r++) { o[0][r] *= sc; o[1][r] *= sc; }
      lsum *= sc;
      m = mn;
    }
    float p[16];
    float rs = 0.f;
#pragma unroll
    for (int r = 0; r < 16; r++) { p[r] = __expf(s[r] - m); rs += p[r]; }
    rs += __shfl_xor(rs, 32);
    lsum += rs;

    // ---- pack P into PV B-frag: 8 cvt_pkrtz + 4 permlane32_swap
    unsigned pw[8];
#pragma unroll
    for (int i = 0; i < 8; i++)
      pw[i] = __builtin_bit_cast(unsigned, __builtin_amdgcn_cvt_pkrtz(p[2 * i], p[2 * i + 1]));
    uint2v s02 = __builtin_amdgcn_permlane32_swap(pw[0], pw[2], false, false);
    uint2v s13 = __builtin_amdgcn_permlane32_swap(pw[1], pw[3], false, false);
    uint2v s46 = __builtin_amdgcn_permlane32_swap(pw[4], pw[6], false, false);
    uint2v s57 = __builtin_amdgcn_permlane32_swap(pw[5], pw[7], false, false);
    union BU { unsigned u[4]; f16x8 v; };
    BU b0, b1;
    b0.u[0] = s02[0]; b0.u[1] = s13[0]; b0.u[2] = s02[1]; b0.u[3] = s13[1];
    b1.u[0] = s46[0]; b1.u[1] = s57[0]; b1.u[2] = s46[1]; b1.u[3] = s57[1];

    // ---- PV: O^T += V^T-frag x P^T-frag
    o[0] = __builtin_amdgcn_mfma_f32_32x32x16_f16(vf00, b0.v, o[0], 0, 0, 0);
    o[0] = __builtin_amdgcn_mfma_f32_32x32x16_f16(vf01, b1.v, o[0], 0, 0, 0);
    o[1] = __builtin_amdgcn_mfma_f32_32x32x16_f16(vf10, b0.v, o[1], 0, 0, 0);
    o[1] = __builtin_amdgcn_mfma_f32_32x32x16_f16(vf11, b1.v, o[1], 0, 0, 0);
  };

  f16x8 ka[4], kb_[4];
  if (t0 < t1) loadK(t0, ka);
  int kt = t0;
  for (; kt + 2 <= t1; kt += 2) { body(kt, ka, kb_); body(kt + 1, kb_, ka); }
  if (kt < t1) body(kt, ka, kb_);

  // ---- combine the two waves' partials (wave1 publishes, wave0 merges)
  if (w == 1) {
#pragma unroll
    for (int dt = 0; dt < 2; dt++)
#pragma unroll
      for (int r = 0; r < 16; r++)
        o_lds[((dt * 16 + r) * 2 + hi) * 32 + lq] = o[dt][r];
    if (hi == 0) { ml_lds[lq] = m; ml_lds[32 + lq] = lsum; }
  }
  __syncthreads();
  if (w == 0) {
    float mB = ml_lds[lq], lB = ml_lds[32 + lq];
    float mf = fmaxf(m, mB);
    float sA = __expf(m - mf), sB = __expf(mB - mf);
    float lf = lsum * sA + lB * sB;
    float inv = 1.0f / lf;
    f16* crow = ctx + ((size_t)(b * S_LEN + q)) * D_MODEL + h * 64;
#pragma unroll
    for (int dt = 0; dt < 2; dt++) {
#pragma unroll
      for (int g = 0; g < 4; g++) {
        f16x4 ov;
#pragma unroll
        for (int c = 0; c < 4; c++) {
          int r = g * 4 + c;
          float vB = o_lds[((dt * 16 + r) * 2 + hi) * 32 + lq];
          ov[c] = (f16)((o[dt][r] * sA + vB * sB) * inv);
        }
        *(f16x4*)(crow + dt * 32 + g * 8 + hi * 4) = ov;
      }
    }
  }
}

extern "C" void kernel_launch(void* const* d_in, const int* in_sizes, int n_in,
                              void* d_out, int out_size, void* d_ws, size_t ws_size,
                              hipStream_t stream) {
  const float* q = (const float*)d_in[0];
  const float* k = (const float*)d_in[1];
  const float* v = (const float*)d_in[2];
  // d_in[3] = mask (causal tril, hardcoded), d_in[4] = max_seq_len (unused)
  const float* Wq = (const float*)d_in[5];
  const float* bq = (const float*)d_in[6];
  const float* Wk = (const float*)d_in[7];
  const float* bk = (const float*)d_in[8];
  const float* Wv = (const float*)d_in[9];
  const float* bv = (const float*)d_in[10];
  const float* Wo = (const float*)d_in[11];
  const float* bo = (const float*)d_in[12];

  char* ws = (char*)d_ws;
  const size_t MB = 1ull << 20;
  f16* qb   = (f16*)(ws + 0 * MB);    // [4096,1024] f16, 8MB each
  f16* kb   = (f16*)(ws + 8 * MB);
  f16* vb   = (f16*)(ws + 16 * MB);
  f16* Wqh  = (f16*)(ws + 24 * MB);   // [1024,1024] f16, 2MB each
  f16* Wkh  = (f16*)(ws + 26 * MB);
  f16* Wvh  = (f16*)(ws + 28 * MB);
  f16* Woh  = (f16*)(ws + 30 * MB);
  f16* Qh   = (f16*)(ws + 32 * MB);   // [B,H,S,64] f16
  f16* Kh   = (f16*)(ws + 40 * MB);
  f16* Vt   = (f16*)(ws + 48 * MB);   // [B,H,64,S] f16
  f16* ctxb = (f16*)(ws + 56 * MB);   // [B,S,D] f16
  float* sin_t = (float*)(ws + 64 * MB);           // [S,32] f32
  float* cos_t = (float*)(ws + 64 * MB + 256 * 1024);

  cvt_all_kernel<<<dim3(2048), dim3(256), 0, stream>>>(
      q, k, v, Wq, Wk, Wv, Wo, qb, kb, vb, Wqh, Wkh, Wvh, Woh);
  rope_table_kernel<<<dim3((S_LEN * 32) / 256), dim3(256), 0, stream>>>(sin_t, cos_t);

  qkv_gemm_kernel<<<dim3(M_TOK / 128, D_MODEL / 128, 3), 256, 0, stream>>>(
      qb, kb, vb, Wqh, Wkh, Wvh, bq, bk, bv, Qh, Kh, Vt, sin_t, cos_t);

  attn_kernel<<<dim3(2048), dim3(128), 0, stream>>>(Qh, Kh, Vt, ctxb);

  out_gemm_kernel<<<dim3(M_TOK / 128, D_MODEL / 128), 256, 0, stream>>>(ctxb, Woh, bo, (float*)d_out);
}